// Round 5
// baseline (285.329 us; speedup 1.0000x reference)
//
#include <hip/hip_runtime.h>

typedef unsigned short u16;
typedef unsigned int   u32;
typedef __bf16  bf16x8 __attribute__((ext_vector_type(8)));
typedef float   f32x4  __attribute__((ext_vector_type(4)));
typedef u16     u16x4  __attribute__((ext_vector_type(4)));
typedef u16     u16x8  __attribute__((ext_vector_type(8)));

#define S_LEN 2048
#define NH 32
#define NKVH 8
#define HD 128
#define QKVST 6144          /* packed QKV row stride  */
#define AOST  4096          /* attn-out row stride    */
#define ATT_SCALE 0.08838834764831845f
#define RESCALE_THR 8.0f

__device__ __forceinline__ u16 f2bf(float f){
  u32 u = __builtin_bit_cast(u32, f);
  u += 0x7FFFu + ((u >> 16) & 1u);
  return (u16)(u >> 16);
}
__device__ __forceinline__ float bf2f(u16 h){
  u32 u = ((u32)h) << 16;
  return __builtin_bit_cast(float, u);
}
// async global->LDS, 16B per lane. Dest must be wave-uniform base + lane*16.
__device__ __forceinline__ void gload_lds16(const u16* g, u16* l){
  __builtin_amdgcn_global_load_lds(
      (const __attribute__((address_space(1))) void*)g,
      (__attribute__((address_space(3))) void*)l, 16, 0, 0);
}

// ---------------- f32 -> bf16 convert (vectorized) ----------------
__global__ void cvt_kernel(const f32x4* __restrict__ in, u16x4* __restrict__ out, int n4){
  int i = blockIdx.x * 256 + threadIdx.x;
  if (i >= n4) return;
  f32x4 v = in[i];
  u16x4 o;
  o[0] = f2bf(v[0]); o[1] = f2bf(v[1]); o[2] = f2bf(v[2]); o[3] = f2bf(v[3]);
  out[i] = o;
}

// ---------------- GEMM: C[M][N] = X[M][K] @ W[N][K]^T (bf16 in, f32 acc) ----
// 128x128 tile, BK=64 (2x [128][32] sub-tiles), double-buffered prefetch.
// ROPE=1 fuses partial RoPE (Q+K cols, n0<5120) and ATT_SCALE (Q cols, n0<4096).
template<int OUT_BF16, int ROPE>
__global__ __launch_bounds__(256, 2)
void gemm_bt_kernel(const u16* __restrict__ X, const u16* __restrict__ W,
                    void* __restrict__ Cv, int M, int N, int K,
                    const float* __restrict__ cosv, const float* __restrict__ sinv){
  __shared__ __align__(16) u16 As[2][2][128 * 32];
  __shared__ __align__(16) u16 Bs[2][2][128 * 32];
  const int m0 = blockIdx.y * 128, n0 = blockIdx.x * 128;
  const int tid = threadIdx.x;
  const int wave = tid >> 6, lane = tid & 63;
  const int wm = wave >> 1, wn = wave & 1;
  const int g = lane >> 4, ln = lane & 15;
  const int r0 = tid >> 2;            // rows 0..63 (tid*16B == linear LDS dest)
  const int cc = (tid & 3) * 8;       // bf16 col within sub-tile BK=32
  f32x4 acc[4][4] = {};
  const u16* xa0 = X + (size_t)(m0 + r0) * K + cc;
  const u16* xa1 = X + (size_t)(m0 + r0 + 64) * K + cc;
  const u16* wb0 = W + (size_t)(n0 + r0) * K + cc;
  const u16* wb1 = W + (size_t)(n0 + r0 + 64) * K + cc;

  auto stage = [&](int buf, int k0){
    #pragma unroll
    for (int s = 0; s < 2; s++){
      const int kc = k0 + s * 32;
      gload_lds16(xa0 + kc, &As[buf][s][tid * 8]);
      gload_lds16(xa1 + kc, &As[buf][s][2048 + tid * 8]);
      gload_lds16(wb0 + kc, &Bs[buf][s][tid * 8]);
      gload_lds16(wb1 + kc, &Bs[buf][s][2048 + tid * 8]);
    }
  };

  stage(0, 0);
  __syncthreads();                       // implicit vmcnt(0): tile 0 ready
  int cur = 0;
  for (int k0 = 0; k0 < K; k0 += 64){
    if (k0 + 64 < K) stage(cur ^ 1, k0 + 64);   // prefetch overlaps compute
    #pragma unroll
    for (int s = 0; s < 2; s++){
      bf16x8 a[4], b[4];
      #pragma unroll
      for (int f = 0; f < 4; f++) a[f] = *(const bf16x8*)&As[cur][s][(wm * 64 + f * 16 + ln) * 32 + g * 8];
      #pragma unroll
      for (int f = 0; f < 4; f++) b[f] = *(const bf16x8*)&Bs[cur][s][(wn * 64 + f * 16 + ln) * 32 + g * 8];
      __builtin_amdgcn_s_setprio(1);
      #pragma unroll
      for (int i = 0; i < 4; i++)
        #pragma unroll
        for (int j = 0; j < 4; j++)
          acc[i][j] = __builtin_amdgcn_mfma_f32_16x16x32_bf16(a[i], b[j], acc[i][j], 0, 0, 0);
      __builtin_amdgcn_s_setprio(0);
    }
    __syncthreads();   // ONE barrier/tile: drains prefetch vmcnt + guards reuse
    cur ^= 1;
  }
  if (ROPE){
    // fused partial RoPE: Q/K column blocks (n0<5120), first-half dims (wn==0)
    if (wn == 0 && n0 < 5120){
      #pragma unroll
      for (int i = 0; i < 4; i++)
        #pragma unroll
        for (int r = 0; r < 4; r++){
          const int row = m0 + wm * 64 + i * 16 + g * 4 + r;
          #pragma unroll
          for (int j = 0; j < 2; j++){
            const int d = j * 16 + ln;               // 0..31, partner d+32
            float c  = cosv[row * 64 + d];
            float sn = sinv[row * 64 + d];
            float x0 = acc[i][j][r], x1 = acc[i][j + 2][r];
            acc[i][j][r]     = x0 * c - x1 * sn;
            acc[i][j + 2][r] = x1 * c + x0 * sn;
          }
        }
    }
    // fold attention scale into Q so attn skips the per-score multiply
    if (n0 < 4096){
      #pragma unroll
      for (int i = 0; i < 4; i++)
        #pragma unroll
        for (int j = 0; j < 4; j++)
          #pragma unroll
          for (int r = 0; r < 4; r++) acc[i][j][r] *= ATT_SCALE;
    }
  }
  // epilogue: C/D layout col = lane&15, row = (lane>>4)*4 + reg  [m89]
  #pragma unroll
  for (int i = 0; i < 4; i++)
    #pragma unroll
    for (int j = 0; j < 4; j++)
      #pragma unroll
      for (int r = 0; r < 4; r++){
        int row = m0 + wm * 64 + i * 16 + g * 4 + r;
        int col = n0 + wn * 64 + j * 16 + ln;
        if (OUT_BF16) ((u16*)Cv)[(size_t)row * N + col] = f2bf(acc[i][j][r]);
        else          ((float*)Cv)[(size_t)row * N + col] = acc[i][j][r];
      }
}

// ---------------- V transpose: VT[kvh][vd][s] from packed QKV -------------
__global__ void vtrans_kernel(const u16* __restrict__ QKV, u16* __restrict__ VT){
  int idx = blockIdx.x * 256 + threadIdx.x;
  if (idx >= NKVH * HD * S_LEN) return;
  int s   = idx & (S_LEN - 1);
  int vd  = (idx >> 11) & (HD - 1);
  int kvh = idx >> 18;
  VT[idx] = QKV[(size_t)s * QKVST + 5120 + kvh * HD + vd];
}

// ---------------- causal flash attention with sink, GQA 4:1 ----------------
// 4 waves/block, 32 q-rows/WAVE (128 q-rows/block) -> K/V LDS reads amortized
// 2x vs 16-row waves. KVBLK=64, double-buffered prefetch, ONE barrier/tile.
// l = sum(exp) via 9th-fragment MFMA against a REGISTER ones-B-frag.
// Q pre-scaled by ATT_SCALE in the QKV GEMM. XCD-aware flat grid (b&7 = kvh).
__global__ __launch_bounds__(256, 2)
void attn_kernel(const u16* __restrict__ QKV, const u16* __restrict__ VT,
                 const float* __restrict__ sinkb, u16* __restrict__ AO){
  __shared__ __align__(16) u16 Ks[2][64 * 128];
  __shared__ __align__(16) u16 Vs[2][128 * 64];
  __shared__ __align__(16) u16 Ps[4][32 * 64];
  const int b   = blockIdx.x;
  const int kvh = b & 7;                 // XCD round-robin -> kvh per XCD
  const int h   = kvh * 4 + ((b >> 3) & 3);
  const int qt  = 15 - (b >> 5);         // longest blocks first (LPT)
  const int tid = threadIdx.x;
  const int w = tid >> 6, lane = tid & 63;
  const int g = lane >> 4, ln = lane & 15;
  const int q0 = qt * 128;
  const int qw = q0 + w * 32;

  const u16* Kbase = QKV + 4096 + kvh * HD;             // + row*QKVST
  const u16* Vbase = VT + (size_t)kvh * HD * S_LEN;     // + vd*S_LEN + k

  auto stage = [&](int buf, int kt){
    const int k0 = kt * 64;
    #pragma unroll
    for (int p = 0; p < 4; p++){
      int idx = p * 256 + tid;
      int r = idx >> 4, c16 = idx & 15;
      gload_lds16(Kbase + (size_t)(k0 + r) * QKVST + ((c16 ^ (r & 7)) * 8), &Ks[buf][idx * 8]);
    }
    #pragma unroll
    for (int p = 0; p < 4; p++){
      int idx = p * 256 + tid;
      int vd = idx >> 3, c8 = idx & 7;
      gload_lds16(Vbase + (size_t)vd * S_LEN + k0 + ((c8 ^ (vd & 7)) * 8), &Vs[buf][idx * 8]);
    }
  };

  // register ones-B-frag for l accumulation: B[k][0] = 1 (lanes ln==0)
  u16x8 ob;
  #pragma unroll
  for (int j = 0; j < 8; j++) ob[j] = (ln == 0) ? (u16)0x3F80 : (u16)0;
  const bf16x8 onesf = __builtin_bit_cast(bf16x8, ob);

  // Q A-frags (pre-scaled): qh selects 16-row half; row = qw + qh*16 + ln
  bf16x8 qf[2][4];
  #pragma unroll
  for (int qh = 0; qh < 2; qh++){
    const u16* qrow = QKV + (size_t)(qw + qh * 16 + ln) * QKVST + h * HD;
    #pragma unroll
    for (int t = 0; t < 4; t++) qf[qh][t] = *(const bf16x8*)(qrow + t * 32 + g * 8);
  }

  f32x4 O[2][8] = {};
  f32x4 L[2] = {};
  float m_r[2][4];
  #pragma unroll
  for (int qh = 0; qh < 2; qh++)
    #pragma unroll
    for (int r = 0; r < 4; r++) m_r[qh][r] = -3.0e38f;

  const int nkt = 2 * qt + 2;
  stage(0, 0);
  __syncthreads();
  int cur = 0;

  for (int kt = 0; kt < nkt; kt++){
    const int k0 = kt * 64;
    if (kt + 1 < nkt) stage(cur ^ 1, kt + 1);   // prefetch overlaps compute

    if (k0 < qw + 32){                          // skip fully-masked tail tiles
      // QK^T: 32 MFMAs, 16 K-frag reads (each serves both q-halves)
      const u16* Kc = Ks[cur];
      f32x4 sc[2][4] = {};
      __builtin_amdgcn_s_setprio(1);
      #pragma unroll
      for (int f = 0; f < 4; f++){
        const int krow = f * 16 + ln;
        #pragma unroll
        for (int t = 0; t < 4; t++){
          bf16x8 kf = *(const bf16x8*)&Kc[krow * 128 + ((t * 32 + g * 8) ^ ((ln & 7) << 3))];
          sc[0][f] = __builtin_amdgcn_mfma_f32_16x16x32_bf16(qf[0][t], kf, sc[0][f], 0, 0, 0);
          sc[1][f] = __builtin_amdgcn_mfma_f32_16x16x32_bf16(qf[1][t], kf, sc[1][f], 0, 0, 0);
        }
      }
      __builtin_amdgcn_s_setprio(0);

      const bool needmask = (k0 + 63 > qw);
      float pv[2][4][4];
      #pragma unroll
      for (int qh = 0; qh < 2; qh++)
        #pragma unroll
        for (int f = 0; f < 4; f++)
          #pragma unroll
          for (int r = 0; r < 4; r++){
            float v = sc[qh][f][r];
            if (needmask && (k0 + f * 16 + ln > qw + qh * 16 + g * 4 + r)) v = -1e30f;
            pv[qh][f][r] = v;
          }
      // per-row tile max
      float mx[2][4];
      #pragma unroll
      for (int qh = 0; qh < 2; qh++)
        #pragma unroll
        for (int r = 0; r < 4; r++){
          float t = fmaxf(fmaxf(pv[qh][0][r], pv[qh][1][r]), fmaxf(pv[qh][2][r], pv[qh][3][r]));
          #pragma unroll
          for (int d = 1; d < 16; d <<= 1) t = fmaxf(t, __shfl_xor(t, d));
          mx[qh][r] = t;
        }
      // defer-max: only rescale when some row grew past THR
      int ok = 1;
      #pragma unroll
      for (int qh = 0; qh < 2; qh++)
        #pragma unroll
        for (int r = 0; r < 4; r++) ok &= (mx[qh][r] <= m_r[qh][r] + RESCALE_THR);
      if (!__all(ok)){
        #pragma unroll
        for (int qh = 0; qh < 2; qh++){
          float sf_[4];
          #pragma unroll
          for (int r = 0; r < 4; r++){
            float mn = fmaxf(m_r[qh][r], mx[qh][r]);
            sf_[r] = __expf(m_r[qh][r] - mn);
            m_r[qh][r] = mn;
          }
          #pragma unroll
          for (int fn = 0; fn < 8; fn++)
            #pragma unroll
            for (int r = 0; r < 4; r++) O[qh][fn][r] *= sf_[r];
          #pragma unroll
          for (int r = 0; r < 4; r++) L[qh][r] *= sf_[r];
        }
      }
      // P = exp(s - m), store bf16 (swizzled) for PV A-frag
      u16* Pw = Ps[w];
      #pragma unroll
      for (int qh = 0; qh < 2; qh++)
        #pragma unroll
        for (int r = 0; r < 4; r++){
          const int row = qh * 16 + g * 4 + r;
          #pragma unroll
          for (int f = 0; f < 4; f++){
            float p = __expf(pv[qh][f][r] - m_r[qh][r]);
            Pw[row * 64 + ((f * 16 + ln) ^ ((row & 7) << 3))] = f2bf(p);
          }
        }
      // PV: 16 V-frag reads serve both q-halves; l via register ones-frag
      const u16* Vc = Vs[cur];
      bf16x8 pa[2][2];
      #pragma unroll
      for (int qh = 0; qh < 2; qh++)
        #pragma unroll
        for (int hf = 0; hf < 2; hf++)
          pa[qh][hf] = *(const bf16x8*)&Pw[(qh * 16 + ln) * 64 + ((hf * 32 + g * 8) ^ ((ln & 7) << 3))];
      __builtin_amdgcn_s_setprio(1);
      #pragma unroll
      for (int fn = 0; fn < 8; fn++){
        const int vr = fn * 16 + ln;
        #pragma unroll
        for (int hf = 0; hf < 2; hf++){
          bf16x8 vf = *(const bf16x8*)&Vc[vr * 64 + ((hf * 32 + g * 8) ^ ((ln & 7) << 3))];
          O[0][fn] = __builtin_amdgcn_mfma_f32_16x16x32_bf16(pa[0][hf], vf, O[0][fn], 0, 0, 0);
          O[1][fn] = __builtin_amdgcn_mfma_f32_16x16x32_bf16(pa[1][hf], vf, O[1][fn], 0, 0, 0);
        }
      }
      #pragma unroll
      for (int qh = 0; qh < 2; qh++)
        #pragma unroll
        for (int hf = 0; hf < 2; hf++)
          L[qh] = __builtin_amdgcn_mfma_f32_16x16x32_bf16(pa[qh][hf], onesf, L[qh], 0, 0, 0);
      __builtin_amdgcn_s_setprio(0);
    }

    __syncthreads();   // ONE barrier/tile: drains prefetch vmcnt + guards reuse
    cur ^= 1;
  }
  // l lives in L[qh][r] of lanes ln==0; broadcast within 16-lane group,
  // then fold sink into the denominator
  float sb = sinkb[h];
  #pragma unroll
  for (int qh = 0; qh < 2; qh++)
    #pragma unroll
    for (int r = 0; r < 4; r++){
      float l = __shfl(L[qh][r], lane & 48);
      float mt = fmaxf(m_r[qh][r], sb);
      float lt = l * __expf(m_r[qh][r] - mt) + __expf(sb - mt);
      float osc = __expf(m_r[qh][r] - mt) / lt;
      #pragma unroll
      for (int fn = 0; fn < 8; fn++)
        AO[(size_t)(qw + qh * 16 + g * 4 + r) * AOST + h * HD + fn * 16 + ln] = f2bf(O[qh][fn][r] * osc);
    }
}

// ---------------- host-side launch ----------------
extern "C" void kernel_launch(void* const* d_in, const int* in_sizes, int n_in,
                              void* d_out, int out_size, void* d_ws, size_t ws_size,
                              hipStream_t stream){
  (void)in_sizes; (void)n_in; (void)out_size; (void)ws_size;
  const float* hs    = (const float*)d_in[0];
  const float* cosv  = (const float*)d_in[1];
  const float* sinv  = (const float*)d_in[2];
  /* d_in[3] attention_mask: pure causal triu(NEG,1) - implemented directly */
  const float* Wq    = (const float*)d_in[4];
  const float* Wk    = (const float*)d_in[5];
  const float* Wv    = (const float*)d_in[6];
  const float* Wo    = (const float*)d_in[7];
  const float* sinkb = (const float*)d_in[8];
  float* out = (float*)d_out;

  char* ws = (char*)d_ws;
  u16* XB    = (u16*)(ws);                  //  8,388,608  X bf16 [2048][2048]
  u16* WQKVB = (u16*)(ws + 8388608);        // 25,165,824  Wqkv bf16 [6144][2048]
  u16* WOB   = (u16*)(ws + 33554432);       // 16,777,216  Wo bf16 [2048][4096]
  u16* QKV   = (u16*)(ws + 50331648);       // 25,165,824  QKV bf16 [2048][6144]
  u16* VT    = (u16*)(ws + 75497472);       //  4,194,304  V^T bf16 [8][128][2048]
  u16* AO    = (u16*)(ws + 79691776);       // 16,777,216  attn out bf16 [2048][4096]

  // converts (Wq/Wk/Wv packed into one [6144][2048] weight)
  cvt_kernel<<<4096, 256, 0, stream>>>((const f32x4*)hs, (u16x4*)XB, 1048576);
  cvt_kernel<<<8192, 256, 0, stream>>>((const f32x4*)Wq, (u16x4*)WQKVB, 2097152);
  cvt_kernel<<<2048, 256, 0, stream>>>((const f32x4*)Wk, (u16x4*)(WQKVB + 4096 * 2048), 524288);
  cvt_kernel<<<2048, 256, 0, stream>>>((const f32x4*)Wv, (u16x4*)(WQKVB + 5120 * 2048), 524288);
  cvt_kernel<<<8192, 256, 0, stream>>>((const f32x4*)Wo, (u16x4*)WOB, 2097152);

  // fused QKV projection + RoPE + Q-scale epilogue: [2048][6144]
  gemm_bt_kernel<1, 1><<<dim3(48, 16), 256, 0, stream>>>(XB, WQKVB, QKV, 2048, 6144, 2048, cosv, sinv);

  // V transpose (V region carries no rope)
  vtrans_kernel<<<8192, 256, 0, stream>>>(QKV, VT);

  // attention: flat 512-block grid (128 q-rows/block), XCD-aligned kvh
  attn_kernel<<<dim3(512), 256, 0, stream>>>(QKV, VT, sinkb, AO);

  // output projection (f32 out)
  gemm_bt_kernel<0, 0><<<dim3(16, 16), 256, 0, stream>>>(AO, WOB, out, 2048, 2048, 4096, nullptr, nullptr);
}

// Round 6
// 278.694 us; speedup vs baseline: 1.0238x; 1.0238x over previous
//
#include <hip/hip_runtime.h>

typedef unsigned short u16;
typedef unsigned int   u32;
typedef __bf16  bf16x8 __attribute__((ext_vector_type(8)));
typedef float   f32x4  __attribute__((ext_vector_type(4)));
typedef u16     u16x4  __attribute__((ext_vector_type(4)));
typedef u16     u16x8  __attribute__((ext_vector_type(8)));

#define S_LEN 2048
#define NH 32
#define NKVH 8
#define HD 128
#define QKVST 6144          /* packed QKV row stride  */
#define AOST  4096          /* attn-out row stride    */
#define ATT_SCALE 0.08838834764831845f
#define RESCALE_THR 8.0f

__device__ __forceinline__ u16 f2bf(float f){
  u32 u = __builtin_bit_cast(u32, f);
  u += 0x7FFFu + ((u >> 16) & 1u);
  return (u16)(u >> 16);
}
__device__ __forceinline__ float bf2f(u16 h){
  u32 u = ((u32)h) << 16;
  return __builtin_bit_cast(float, u);
}
// async global->LDS, 16B per lane. Dest must be wave-uniform base + lane*16.
__device__ __forceinline__ void gload_lds16(const u16* g, u16* l){
  __builtin_amdgcn_global_load_lds(
      (const __attribute__((address_space(1))) void*)g,
      (__attribute__((address_space(3))) void*)l, 16, 0, 0);
}

// ------------- fused f32 -> bf16 convert of ALL inputs (one launch) --------
// ws layout is contiguous & source-ordered: XB | Wq | Wk | Wv | Wo
__global__ void cvt_all_kernel(const f32x4* __restrict__ hs, const f32x4* __restrict__ wq,
                               const f32x4* __restrict__ wk, const f32x4* __restrict__ wv,
                               const f32x4* __restrict__ wo, u16x4* __restrict__ out){
  int i = blockIdx.x * 256 + threadIdx.x;          // 0 .. 6291455
  const f32x4* src; int off;
  if      (i < 1048576){ src = hs; off = i; }
  else if (i < 3145728){ src = wq; off = i - 1048576; }
  else if (i < 3670016){ src = wk; off = i - 3145728; }
  else if (i < 4194304){ src = wv; off = i - 3670016; }
  else                 { src = wo; off = i - 4194304; }
  f32x4 v = src[off];
  u16x4 o;
  o[0] = f2bf(v[0]); o[1] = f2bf(v[1]); o[2] = f2bf(v[2]); o[3] = f2bf(v[3]);
  out[i] = o;
}

// ---------------- GEMM: C[M][N] = X[M][K] @ W[N][K]^T (bf16 in, f32 acc) ----
// 128x128 tile, BK=64 (2x [128][32] sub-tiles), double-buffered prefetch.
// ROPE=1 fuses partial RoPE (Q+K cols, n0<5120) and ATT_SCALE (Q cols, n0<4096).
template<int OUT_BF16, int ROPE>
__global__ __launch_bounds__(256, 2)
void gemm_bt_kernel(const u16* __restrict__ X, const u16* __restrict__ W,
                    void* __restrict__ Cv, int M, int N, int K,
                    const float* __restrict__ cosv, const float* __restrict__ sinv){
  __shared__ __align__(16) u16 As[2][2][128 * 32];
  __shared__ __align__(16) u16 Bs[2][2][128 * 32];
  const int m0 = blockIdx.y * 128, n0 = blockIdx.x * 128;
  const int tid = threadIdx.x;
  const int wave = tid >> 6, lane = tid & 63;
  const int wm = wave >> 1, wn = wave & 1;
  const int g = lane >> 4, ln = lane & 15;
  const int r0 = tid >> 2;            // rows 0..63 (tid*16B == linear LDS dest)
  const int cc = (tid & 3) * 8;       // bf16 col within sub-tile BK=32
  f32x4 acc[4][4] = {};
  const u16* xa0 = X + (size_t)(m0 + r0) * K + cc;
  const u16* xa1 = X + (size_t)(m0 + r0 + 64) * K + cc;
  const u16* wb0 = W + (size_t)(n0 + r0) * K + cc;
  const u16* wb1 = W + (size_t)(n0 + r0 + 64) * K + cc;

  auto stage = [&](int buf, int k0){
    #pragma unroll
    for (int s = 0; s < 2; s++){
      const int kc = k0 + s * 32;
      gload_lds16(xa0 + kc, &As[buf][s][tid * 8]);
      gload_lds16(xa1 + kc, &As[buf][s][2048 + tid * 8]);
      gload_lds16(wb0 + kc, &Bs[buf][s][tid * 8]);
      gload_lds16(wb1 + kc, &Bs[buf][s][2048 + tid * 8]);
    }
  };

  stage(0, 0);
  __syncthreads();                       // implicit vmcnt(0): tile 0 ready
  int cur = 0;
  for (int k0 = 0; k0 < K; k0 += 64){
    if (k0 + 64 < K) stage(cur ^ 1, k0 + 64);   // prefetch overlaps compute
    #pragma unroll
    for (int s = 0; s < 2; s++){
      bf16x8 a[4], b[4];
      #pragma unroll
      for (int f = 0; f < 4; f++) a[f] = *(const bf16x8*)&As[cur][s][(wm * 64 + f * 16 + ln) * 32 + g * 8];
      #pragma unroll
      for (int f = 0; f < 4; f++) b[f] = *(const bf16x8*)&Bs[cur][s][(wn * 64 + f * 16 + ln) * 32 + g * 8];
      __builtin_amdgcn_s_setprio(1);
      #pragma unroll
      for (int i = 0; i < 4; i++)
        #pragma unroll
        for (int j = 0; j < 4; j++)
          acc[i][j] = __builtin_amdgcn_mfma_f32_16x16x32_bf16(a[i], b[j], acc[i][j], 0, 0, 0);
      __builtin_amdgcn_s_setprio(0);
    }
    __syncthreads();   // ONE barrier/tile: drains prefetch vmcnt + guards reuse
    cur ^= 1;
  }
  if (ROPE){
    // fused partial RoPE: Q/K column blocks (n0<5120), first-half dims (wn==0)
    if (wn == 0 && n0 < 5120){
      #pragma unroll
      for (int i = 0; i < 4; i++)
        #pragma unroll
        for (int r = 0; r < 4; r++){
          const int row = m0 + wm * 64 + i * 16 + g * 4 + r;
          #pragma unroll
          for (int j = 0; j < 2; j++){
            const int d = j * 16 + ln;               // 0..31, partner d+32
            float c  = cosv[row * 64 + d];
            float sn = sinv[row * 64 + d];
            float x0 = acc[i][j][r], x1 = acc[i][j + 2][r];
            acc[i][j][r]     = x0 * c - x1 * sn;
            acc[i][j + 2][r] = x1 * c + x0 * sn;
          }
        }
    }
    // fold attention scale into Q so attn skips the per-score multiply
    if (n0 < 4096){
      #pragma unroll
      for (int i = 0; i < 4; i++)
        #pragma unroll
        for (int j = 0; j < 4; j++)
          #pragma unroll
          for (int r = 0; r < 4; r++) acc[i][j][r] *= ATT_SCALE;
    }
  }
  // epilogue: C/D layout col = lane&15, row = (lane>>4)*4 + reg  [m89]
  #pragma unroll
  for (int i = 0; i < 4; i++)
    #pragma unroll
    for (int j = 0; j < 4; j++)
      #pragma unroll
      for (int r = 0; r < 4; r++){
        int row = m0 + wm * 64 + i * 16 + g * 4 + r;
        int col = n0 + wn * 64 + j * 16 + ln;
        if (OUT_BF16) ((u16*)Cv)[(size_t)row * N + col] = f2bf(acc[i][j][r]);
        else          ((float*)Cv)[(size_t)row * N + col] = acc[i][j][r];
      }
}

// ---------------- V transpose: VT[kvh][vd][s] from packed QKV -------------
__global__ void vtrans_kernel(const u16* __restrict__ QKV, u16* __restrict__ VT){
  int idx = blockIdx.x * 256 + threadIdx.x;
  if (idx >= NKVH * HD * S_LEN) return;
  int s   = idx & (S_LEN - 1);
  int vd  = (idx >> 11) & (HD - 1);
  int kvh = idx >> 18;
  VT[idx] = QKV[(size_t)s * QKVST + 5120 + kvh * HD + vd];
}

// ---------------- causal flash attention with sink, GQA 4:1 ----------------
// 4 waves/block, 32 q-rows/WAVE (128 q-rows/block). LDS = 72KB -> 2 blocks/CU
// (R5's 80KB broke co-residency: occupancy 21%->12.8%, dur 87->111us).
// Ps is 16 rows/wave, processed per q-half (wave-local LDS is in-order).
// KVBLK=64, double-buffered prefetch, ONE barrier/tile. l via register
// ones-B-frag MFMA. Q pre-scaled. XCD-aware flat grid (b&7 = kvh).
__global__ __launch_bounds__(256, 2)
void attn_kernel(const u16* __restrict__ QKV, const u16* __restrict__ VT,
                 const float* __restrict__ sinkb, u16* __restrict__ AO){
  __shared__ __align__(16) u16 Ks[2][64 * 128];
  __shared__ __align__(16) u16 Vs[2][128 * 64];
  __shared__ __align__(16) u16 Ps[4][16 * 64];
  const int b   = blockIdx.x;
  const int kvh = b & 7;                 // XCD round-robin -> kvh per XCD
  const int h   = kvh * 4 + ((b >> 3) & 3);
  const int qt  = 15 - (b >> 5);         // longest blocks first (LPT)
  const int tid = threadIdx.x;
  const int w = tid >> 6, lane = tid & 63;
  const int g = lane >> 4, ln = lane & 15;
  const int q0 = qt * 128;
  const int qw = q0 + w * 32;

  const u16* Kbase = QKV + 4096 + kvh * HD;             // + row*QKVST
  const u16* Vbase = VT + (size_t)kvh * HD * S_LEN;     // + vd*S_LEN + k

  auto stage = [&](int buf, int kt){
    const int k0 = kt * 64;
    #pragma unroll
    for (int p = 0; p < 4; p++){
      int idx = p * 256 + tid;
      int r = idx >> 4, c16 = idx & 15;
      gload_lds16(Kbase + (size_t)(k0 + r) * QKVST + ((c16 ^ (r & 7)) * 8), &Ks[buf][idx * 8]);
    }
    #pragma unroll
    for (int p = 0; p < 4; p++){
      int idx = p * 256 + tid;
      int vd = idx >> 3, c8 = idx & 7;
      gload_lds16(Vbase + (size_t)vd * S_LEN + k0 + ((c8 ^ (vd & 7)) * 8), &Vs[buf][idx * 8]);
    }
  };

  // register ones-B-frag for l accumulation: B[k][0] = 1 (lanes ln==0)
  u16x8 ob;
  #pragma unroll
  for (int j = 0; j < 8; j++) ob[j] = (ln == 0) ? (u16)0x3F80 : (u16)0;
  const bf16x8 onesf = __builtin_bit_cast(bf16x8, ob);

  // Q A-frags (pre-scaled): qh selects 16-row half; row = qw + qh*16 + ln
  bf16x8 qf[2][4];
  #pragma unroll
  for (int qh = 0; qh < 2; qh++){
    const u16* qrow = QKV + (size_t)(qw + qh * 16 + ln) * QKVST + h * HD;
    #pragma unroll
    for (int t = 0; t < 4; t++) qf[qh][t] = *(const bf16x8*)(qrow + t * 32 + g * 8);
  }

  f32x4 O[2][8] = {};
  f32x4 L[2] = {};
  float m_r[2][4];
  #pragma unroll
  for (int qh = 0; qh < 2; qh++)
    #pragma unroll
    for (int r = 0; r < 4; r++) m_r[qh][r] = -3.0e38f;

  const int nkt = 2 * qt + 2;
  stage(0, 0);
  __syncthreads();
  int cur = 0;

  for (int kt = 0; kt < nkt; kt++){
    const int k0 = kt * 64;
    if (kt + 1 < nkt) stage(cur ^ 1, kt + 1);   // prefetch overlaps compute

    if (k0 < qw + 32){                          // skip fully-masked tail tiles
      // QK^T: 32 MFMAs, 16 K-frag reads (each serves both q-halves)
      const u16* Kc = Ks[cur];
      f32x4 sc[2][4] = {};
      __builtin_amdgcn_s_setprio(1);
      #pragma unroll
      for (int f = 0; f < 4; f++){
        const int krow = f * 16 + ln;
        #pragma unroll
        for (int t = 0; t < 4; t++){
          bf16x8 kf = *(const bf16x8*)&Kc[krow * 128 + ((t * 32 + g * 8) ^ ((ln & 7) << 3))];
          sc[0][f] = __builtin_amdgcn_mfma_f32_16x16x32_bf16(qf[0][t], kf, sc[0][f], 0, 0, 0);
          sc[1][f] = __builtin_amdgcn_mfma_f32_16x16x32_bf16(qf[1][t], kf, sc[1][f], 0, 0, 0);
        }
      }
      __builtin_amdgcn_s_setprio(0);

      const bool needmask = (k0 + 63 > qw);
      float pv[2][4][4];
      #pragma unroll
      for (int qh = 0; qh < 2; qh++)
        #pragma unroll
        for (int f = 0; f < 4; f++)
          #pragma unroll
          for (int r = 0; r < 4; r++){
            float v = sc[qh][f][r];
            if (needmask && (k0 + f * 16 + ln > qw + qh * 16 + g * 4 + r)) v = -1e30f;
            pv[qh][f][r] = v;
          }
      // per-row tile max
      float mx[2][4];
      #pragma unroll
      for (int qh = 0; qh < 2; qh++)
        #pragma unroll
        for (int r = 0; r < 4; r++){
          float t = fmaxf(fmaxf(pv[qh][0][r], pv[qh][1][r]), fmaxf(pv[qh][2][r], pv[qh][3][r]));
          #pragma unroll
          for (int d = 1; d < 16; d <<= 1) t = fmaxf(t, __shfl_xor(t, d));
          mx[qh][r] = t;
        }
      // defer-max: only rescale when some row grew past THR
      int ok = 1;
      #pragma unroll
      for (int qh = 0; qh < 2; qh++)
        #pragma unroll
        for (int r = 0; r < 4; r++) ok &= (mx[qh][r] <= m_r[qh][r] + RESCALE_THR);
      if (!__all(ok)){
        #pragma unroll
        for (int qh = 0; qh < 2; qh++){
          float sf_[4];
          #pragma unroll
          for (int r = 0; r < 4; r++){
            float mn = fmaxf(m_r[qh][r], mx[qh][r]);
            sf_[r] = __expf(m_r[qh][r] - mn);
            m_r[qh][r] = mn;
          }
          #pragma unroll
          for (int fn = 0; fn < 8; fn++)
            #pragma unroll
            for (int r = 0; r < 4; r++) O[qh][fn][r] *= sf_[r];
          #pragma unroll
          for (int r = 0; r < 4; r++) L[qh][r] *= sf_[r];
        }
      }
      // P = exp(s - m): per q-half, write 16 rows then read that half's
      // A-frags (wave-local LDS ops execute in order -> no barrier needed;
      // the qh=1 write safely lands after the qh=0 reads)
      u16* Pw = Ps[w];
      bf16x8 pa[2][2];
      #pragma unroll
      for (int qh = 0; qh < 2; qh++){
        #pragma unroll
        for (int r = 0; r < 4; r++){
          const int row = g * 4 + r;
          #pragma unroll
          for (int f = 0; f < 4; f++){
            float p = __expf(pv[qh][f][r] - m_r[qh][r]);
            Pw[row * 64 + ((f * 16 + ln) ^ ((row & 7) << 3))] = f2bf(p);
          }
        }
        #pragma unroll
        for (int hf = 0; hf < 2; hf++)
          pa[qh][hf] = *(const bf16x8*)&Pw[ln * 64 + ((hf * 32 + g * 8) ^ ((ln & 7) << 3))];
      }
      // PV: 16 V-frag reads serve both q-halves; l via register ones-frag
      const u16* Vc = Vs[cur];
      __builtin_amdgcn_s_setprio(1);
      #pragma unroll
      for (int fn = 0; fn < 8; fn++){
        const int vr = fn * 16 + ln;
        #pragma unroll
        for (int hf = 0; hf < 2; hf++){
          bf16x8 vf = *(const bf16x8*)&Vc[vr * 64 + ((hf * 32 + g * 8) ^ ((ln & 7) << 3))];
          O[0][fn] = __builtin_amdgcn_mfma_f32_16x16x32_bf16(pa[0][hf], vf, O[0][fn], 0, 0, 0);
          O[1][fn] = __builtin_amdgcn_mfma_f32_16x16x32_bf16(pa[1][hf], vf, O[1][fn], 0, 0, 0);
        }
      }
      #pragma unroll
      for (int qh = 0; qh < 2; qh++)
        #pragma unroll
        for (int hf = 0; hf < 2; hf++)
          L[qh] = __builtin_amdgcn_mfma_f32_16x16x32_bf16(pa[qh][hf], onesf, L[qh], 0, 0, 0);
      __builtin_amdgcn_s_setprio(0);
    }

    __syncthreads();   // ONE barrier/tile: drains prefetch vmcnt + guards reuse
    cur ^= 1;
  }
  // l lives in L[qh][r] of lanes ln==0; broadcast within 16-lane group,
  // then fold sink into the denominator
  float sb = sinkb[h];
  #pragma unroll
  for (int qh = 0; qh < 2; qh++)
    #pragma unroll
    for (int r = 0; r < 4; r++){
      float l = __shfl(L[qh][r], lane & 48);
      float mt = fmaxf(m_r[qh][r], sb);
      float lt = l * __expf(m_r[qh][r] - mt) + __expf(sb - mt);
      float osc = __expf(m_r[qh][r] - mt) / lt;
      #pragma unroll
      for (int fn = 0; fn < 8; fn++)
        AO[(size_t)(qw + qh * 16 + g * 4 + r) * AOST + h * HD + fn * 16 + ln] = f2bf(O[qh][fn][r] * osc);
    }
}

// ---------------- host-side launch ----------------
extern "C" void kernel_launch(void* const* d_in, const int* in_sizes, int n_in,
                              void* d_out, int out_size, void* d_ws, size_t ws_size,
                              hipStream_t stream){
  (void)in_sizes; (void)n_in; (void)out_size; (void)ws_size;
  const float* hs    = (const float*)d_in[0];
  const float* cosv  = (const float*)d_in[1];
  const float* sinv  = (const float*)d_in[2];
  /* d_in[3] attention_mask: pure causal triu(NEG,1) - implemented directly */
  const float* Wq    = (const float*)d_in[4];
  const float* Wk    = (const float*)d_in[5];
  const float* Wv    = (const float*)d_in[6];
  const float* Wo    = (const float*)d_in[7];
  const float* sinkb = (const float*)d_in[8];
  float* out = (float*)d_out;

  char* ws = (char*)d_ws;
  u16* XB    = (u16*)(ws);                  //  8,388,608  X bf16 [2048][2048]
  u16* WQKVB = (u16*)(ws + 8388608);        // 25,165,824  Wqkv bf16 [6144][2048]
  u16* WOB   = (u16*)(ws + 33554432);       // 16,777,216  Wo bf16 [2048][4096]
  u16* QKV   = (u16*)(ws + 50331648);       // 25,165,824  QKV bf16 [2048][6144]
  u16* VT    = (u16*)(ws + 75497472);       //  4,194,304  V^T bf16 [8][128][2048]
  u16* AO    = (u16*)(ws + 79691776);       // 16,777,216  attn out bf16 [2048][4096]

  // single fused convert: hs|Wq|Wk|Wv|Wo -> XB|WQKVB|WOB (contiguous in ws)
  cvt_all_kernel<<<24576, 256, 0, stream>>>((const f32x4*)hs, (const f32x4*)Wq,
                                            (const f32x4*)Wk, (const f32x4*)Wv,
                                            (const f32x4*)Wo, (u16x4*)ws);

  // fused QKV projection + RoPE + Q-scale epilogue: [2048][6144]
  gemm_bt_kernel<1, 1><<<dim3(48, 16), 256, 0, stream>>>(XB, WQKVB, QKV, 2048, 6144, 2048, cosv, sinv);

  // V transpose (V region carries no rope)
  vtrans_kernel<<<8192, 256, 0, stream>>>(QKV, VT);

  // attention: flat 512-block grid (128 q-rows/block), XCD-aligned kvh
  attn_kernel<<<dim3(512), 256, 0, stream>>>(QKV, VT, sinkb, AO);

  // output projection (f32 out)
  gemm_bt_kernel<0, 0><<<dim3(16, 16), 256, 0, stream>>>(AO, WOB, out, 2048, 2048, 4096, nullptr, nullptr);
}